// Round 25
// baseline (107.417 us; speedup 1.0000x reference)
//
#include <hip/hip_runtime.h>
#include <hip/hip_bf16.h>
#include <math.h>

// Problem constants (N_WAY=64, K_SHOT=5, Q_QUERY=128, D_FEAT=128)
#define M     8192      // n*q query rows
#define D     128       // feature dim
#define NCLS  64        // n classes
#define KSHOT 5
#define XROW  133       // (k+q) rows per class in x
#define KTOP  9
#define EPSV  1e-8f

// Threshold filter + exact certificate (R13) + packed-value segments (R18)
// + bisection select (R19) + 128-i blocks (R20) + R24 tightening:
//   k2f packs (bf16(v)<<16 | j) for v >= TAU_LO into per-(row,j-split)
//   segments (LDS-counter emission, zero global atomics). k_rr finds the
//   9th-largest STORED value via 9-step integer bisection, exact-re-dots only
//   stored >= v9s - 2*EPS_STORE (provable superset of the exact top-9:
//   exact9th >= v9s - 0.004; top-9 member x has stored(x) >= exact(x) -
//   0.004(mfma) - 0.002(trunc) >= v9s - 0.010 > v9s - 0.012 = th),
//   certifies exact-9th > TAU_LO + EPS_DOT, else inline full-row fallback
//   (P ~ 1e-13/row; do NOT raise TAU_LO -- straggler fallback ~450us, R12).
// R21/R22 lesson: k_rr is occupancy/latency-bound; ILP machinery that adds
//   VGPRs loses. R24: EPS_STORE 0.008->0.006 (~25% fewer serial re-dots) +
//   1-deep candidate prefetch (R17 pattern, measured register-neutral).
#define TAU_LO    0.21f
#define EPS_DOT   0.005f
#define EPS_STORE 0.006f    // mfma err 0.004 + bf16 truncation 0.002
#define CAPB      24        // per-(row, j-split) segment capacity (lambda ~4.3)

#define BI    128           // i rows per block in k2f
#define SJ    16
#define JPB   (M / SJ)      // 512 j per block
#define NTIL  (JPB / 16)    // 32 j-tiles of 16
#define NRND  6             // max pair rounds in k_rr (16*24/64 = 6)

typedef __attribute__((__ext_vector_type__(8))) short bf16v8;  // 8 bf16 = 4 VGPR
typedef __attribute__((__ext_vector_type__(4))) float f32v4;

// ---------------------------------------------------------------------------
// register-resident top-K with (value desc, index asc) tie-break, matching
// jax.lax.top_k set semantics; arrival-order independent for distinct indices.
template <int KN>
__device__ __forceinline__ void topk_insert(float (&kv)[KN], int (&ki)[KN],
                                            float v, int j) {
  if (v > kv[KN - 1] || (v == kv[KN - 1] && j < ki[KN - 1])) {
    float cv = v; int cj = j;
#pragma unroll
    for (int t = 0; t < KN; ++t) {
      bool b = (cv > kv[t]) || (cv == kv[t] && cj < ki[t]);
      float tv = kv[t]; int ti_ = ki[t];
      kv[t] = b ? cv : tv;  ki[t] = b ? cj : ti_;
      cv   = b ? tv : cv;   cj   = b ? ti_ : cj;
    }
  }
}

// ---------------------------------------------------------------------------
__global__ void k0_proto(const float* __restrict__ x, float* __restrict__ protnT) {
  int c = blockIdx.x;
  int lane = threadIdx.x;
  const float* base = x + (size_t)(c * XROW) * D;
  float a0 = 0.f, a1 = 0.f;
#pragma unroll
  for (int s = 0; s < KSHOT; ++s) {
    a0 += base[s * D + lane];
    a1 += base[s * D + 64 + lane];
  }
  a0 *= 0.2f; a1 *= 0.2f;
  float ss = a0 * a0 + a1 * a1;
#pragma unroll
  for (int off = 1; off < 64; off <<= 1) ss += __shfl_xor(ss, off);
  float rn = 1.0f / fmaxf(sqrtf(ss), EPSV);
  protnT[lane * NCLS + c]        = a0 * rn;
  protnT[(lane + 64) * NCLS + c] = a1 * rn;
}

// ---------------------------------------------------------------------------
// k1: L2-normalize query rows -> qn (f32) and qh (bf16).
__global__ void k1_qnorm(const float* __restrict__ x, float* __restrict__ qn,
                         short* __restrict__ qh) {
  int lane = threadIdx.x & 63;
  int wv = threadIdx.x >> 6;
  int r = blockIdx.x * 4 + wv;
  int xr = (r >> 7) * XROW + KSHOT + (r & 127);
  const float* src = x + (size_t)xr * D;
  float v0 = src[lane], v1 = src[64 + lane];
  float ss = v0 * v0 + v1 * v1;
#pragma unroll
  for (int off = 1; off < 64; off <<= 1) ss += __shfl_xor(ss, off);
  float rn = 1.0f / fmaxf(sqrtf(ss), EPSV);
  float q0 = v0 * rn, q1 = v1 * rn;
  qn[(size_t)r * D + lane]      = q0;
  qn[(size_t)r * D + 64 + lane] = q1;
  __hip_bfloat16 h0 = __float2bfloat16(q0);
  __hip_bfloat16 h1 = __float2bfloat16(q1);
  qh[(size_t)r * D + lane]      = *(short*)&h0;
  qh[(size_t)r * D + 64 + lane] = *(short*)&h1;
}

// ---------------------------------------------------------------------------
// k2f: bf16 MFMA + threshold filter. LDS-staged double-buffered j-tile,
// 128 i-rows/block (2 i-subs share each A-frag ds_read), LDS per-row
// counters, per-(row, j-split) segments of packed (bf16(v)<<16|j).
// D layout (m89-verified): i-col = lane&15, j-row = (lane>>4)*4 + reg.
// (Frozen since R20.)
__global__ __launch_bounds__(256) void
k2f(const short* __restrict__ qh, int* __restrict__ segcnt,
    unsigned* __restrict__ cand) {
  __shared__ __align__(16) short jh[2][16 * D];   // 2 x 4 KB j-tile
  __shared__ int lcnt[BI];

  const int tid  = threadIdx.x;
  const int l    = tid & 63;
  const int w    = tid >> 6;
  const int ib   = blockIdx.x >> 4;        // 64 i-strips of 128
  const int js   = blockIdx.x & (SJ - 1);  // 16 j-splits
  const int i0   = ib * BI;
  const int j0s  = js * JPB;

  if (tid < BI) lcnt[tid] = 0;

  const bf16v8* qh8 = (const bf16v8*)qh;
  const int lg   = l >> 4;                 // k-group 0..3
  const int arow = l & 15;
  const int lrow = w * 16 + arow;          // local row 0..63 (i-sub 0)
  const int myi  = i0 + lrow;              // i-sub 0 row
  const int myi2 = myi + 64;               // i-sub 1 row

  bf16v8 bh[4], bg[4];
#pragma unroll
  for (int kk = 0; kk < 4; ++kk) {
    bh[kk] = qh8[(size_t)myi  * 16 + kk * 4 + lg];
    bg[kk] = qh8[(size_t)myi2 * 16 + kk * 4 + lg];
  }

  const int srow = tid >> 4;
  const int schk = tid & 15;
  const int sslot = srow * 16 + (schk ^ (srow & 7));
  int rslot[4];
#pragma unroll
  for (int kk = 0; kk < 4; ++kk)
    rslot[kk] = arow * 16 + ((kk * 4 + lg) ^ (arow & 7));

  unsigned* seg  = cand + ((size_t)myi  * SJ + js) * CAPB;
  unsigned* seg2 = cand + ((size_t)myi2 * SJ + js) * CAPB;

  bf16v8 sa = qh8[(size_t)(j0s + srow) * 16 + schk];
  ((bf16v8*)jh[0])[sslot] = sa;
  sa = qh8[(size_t)(j0s + 16 + srow) * 16 + schk];
  __syncthreads();                         // covers lcnt init + buf0

  for (int t = 0; t < NTIL; ++t) {
    if (t + 1 < NTIL) {
      ((bf16v8*)jh[(t + 1) & 1])[sslot] = sa;
      if (t + 2 < NTIL)
        sa = qh8[(size_t)(j0s + (t + 2) * 16 + srow) * 16 + schk];
    }

    const bf16v8* H = (const bf16v8*)jh[t & 1];
    f32v4 a0 = {0.f, 0.f, 0.f, 0.f};
    f32v4 a1 = {0.f, 0.f, 0.f, 0.f};
    f32v4 c0 = {0.f, 0.f, 0.f, 0.f};
    f32v4 c1 = {0.f, 0.f, 0.f, 0.f};
#pragma unroll
    for (int kk = 0; kk < 4; ++kk) {
      bf16v8 ah = H[rslot[kk]];            // one ds_read feeds both i-subs
      if (kk & 1) {
        a1 = __builtin_amdgcn_mfma_f32_16x16x32_bf16(ah, bh[kk], a1, 0, 0, 0);
        c1 = __builtin_amdgcn_mfma_f32_16x16x32_bf16(ah, bg[kk], c1, 0, 0, 0);
      } else {
        a0 = __builtin_amdgcn_mfma_f32_16x16x32_bf16(ah, bh[kk], a0, 0, 0, 0);
        c0 = __builtin_amdgcn_mfma_f32_16x16x32_bf16(ah, bg[kk], c0, 0, 0, 0);
      }
    }
    f32v4 s = a0 + a1;
    f32v4 r2 = c0 + c1;

    const int jb = j0s + t * 16 + lg * 4;
#pragma unroll
    for (int u = 0; u < 4; ++u) {
      if (s[u] >= TAU_LO) {                // ~0.9% of values
        int slot = atomicAdd(&lcnt[lrow], 1);
        if (slot < CAPB)
          seg[slot] = (__float_as_uint(s[u]) & 0xFFFF0000u) | (unsigned)(jb + u);
      }
      if (r2[u] >= TAU_LO) {
        int slot = atomicAdd(&lcnt[lrow + 64], 1);
        if (slot < CAPB)
          seg2[slot] = (__float_as_uint(r2[u]) & 0xFFFF0000u) | (unsigned)(jb + u);
      }
    }

    __syncthreads();
  }

  if (tid < BI)
    segcnt[(size_t)(i0 + tid) * SJ + js] = lcnt[tid];
}

// ---------------------------------------------------------------------------
// k_rr v7 = v3 serial body + dead-round skip + 9-step bisection +
// 1-deep candidate prefetch (R17 pattern; register-neutral) +
// EPS_STORE=0.006 (~25% fewer serial re-dots).
__global__ void k_rr(const float* __restrict__ qn, const int* __restrict__ segcnt,
                     const unsigned* __restrict__ cand,
                     float* __restrict__ kval, int* __restrict__ kidx) {
  __shared__ float qi_s[4][D];
  int lane = threadIdx.x & 63;
  int wv   = threadIdx.x >> 6;
  int i = blockIdx.x * 4 + wv;

  float qi0 = qn[(size_t)i * D + lane];
  float qi1 = qn[(size_t)i * D + 64 + lane];

  // --- segment counts + prefix scan (lanes 0..15) ---
  int sc = (lane < SJ) ? segcnt[(size_t)i * SJ + lane] : 0;
  bool bad = __any(lane < SJ && sc > CAPB);
  int pre = sc;
#pragma unroll
  for (int off = 1; off < 16; off <<= 1) {
    int o = __shfl_up(pre, off, 16);
    if ((lane & 15) >= off) pre += o;
  }
  int b[SJ];                               // inclusive prefix, all lanes
#pragma unroll
  for (int k = 0; k < SJ; ++k) b[k] = __shfl(pre, k);
  const int ct = b[SJ - 1];
  bad = bad || (ct < KTOP);
  const int nra = (ct + 63) >> 6;          // active rounds, wave-uniform

  // --- lane-parallel packed-pair load (dead rounds skipped, NO inserts) ---
  const unsigned* crow = cand + (size_t)i * SJ * CAPB;
  float vv[NRND]; int jj[NRND];
#pragma unroll
  for (int r = 0; r < NRND; ++r) {
    vv[r] = 0.f; jj[r] = 0;
    if (r < nra) {                         // wave-uniform guard, static index
      int t = r * 64 + lane;
      bool valid = t < ct;
      int s = 0, off = 0;
#pragma unroll
      for (int k = 0; k < SJ; ++k) {       // b nondecreasing -> cmov scan
        bool ge = t >= b[k];
        s   = ge ? k + 1 : s;
        off = ge ? b[k] : off;
      }
      unsigned u = valid ? crow[s * CAPB + (t - off)] : 0u;
      vv[r] = __uint_as_float(u & 0xFFFF0000u);  // exact bf16 payload (>=0)
      jj[r] = (int)(u & 8191u);
    }
  }

  // --- bisect 9th-largest stored value; stored in [bf16(0.21)=0x3E57, ~0x3F81]
  //     so [0x3E00, 0x3FFF] covers it; ct>=9 keeps the invariant at lo ---
  int lo = 0x3E00, hi = 0x3FFF;
  while (lo < hi) {                        // 9 uniform iterations
    int mid = (lo + hi + 1) >> 1;
    unsigned um = (unsigned)mid << 16;
    int cnt = 0;
#pragma unroll
    for (int r = 0; r < NRND; ++r)
      if (r < nra)
        cnt += (int)__popcll(__ballot(__float_as_uint(vv[r]) >= um));
    if (cnt >= KTOP) lo = mid; else hi = mid - 1;
  }
  const float th = __uint_as_float((unsigned)lo << 16) - 2.0f * EPS_STORE;

  // --- serial exact re-dot of the borderline set (~10/row), 1-deep prefetch ---
  float kv[KTOP]; int ki[KTOP];
#pragma unroll
  for (int t = 0; t < KTOP; ++t) { kv[t] = -INFINITY; ki[t] = 0x7fffffff; }
  if (!bad) {
#pragma unroll
    for (int r = 0; r < NRND; ++r) {
      if (r >= nra) continue;              // wave-uniform
      unsigned long long mask = __ballot(vv[r] >= th);   // invalids are 0 < th
      if (mask == 0ull) continue;          // wave-uniform
      int bl = (int)__ffsll((long long)mask) - 1;
      mask &= mask - 1;
      int jc = __shfl(jj[r], bl);          // wave-uniform
      float b0 = qn[(size_t)jc * D + lane];
      float b1 = qn[(size_t)jc * D + 64 + lane];
      for (;;) {
        int jn = -1; float c0 = 0.f, c1 = 0.f;
        if (mask) {                        // issue NEXT row's loads first
          int bl2 = (int)__ffsll((long long)mask) - 1;
          mask &= mask - 1;
          jn = __shfl(jj[r], bl2);
          c0 = qn[(size_t)jn * D + lane];
          c1 = qn[(size_t)jn * D + 64 + lane];
        }
        float p = qi0 * b0 + qi1 * b1;     // current dot + reduce (hides loads)
#pragma unroll
        for (int off = 1; off < 64; off <<= 1) p += __shfl_xor(p, off);
        topk_insert<KTOP>(kv, ki, p, jc);
        if (jn < 0) break;
        jc = jn; b0 = c0; b1 = c1;
      }
    }
  }

  // --- certificate; else inline exact full-row fallback ---
  if (bad || kv[KTOP - 1] <= TAU_LO + EPS_DOT) {
    qi_s[wv][lane]      = qi0;
    qi_s[wv][64 + lane] = qi1;
#pragma unroll
    for (int t = 0; t < KTOP; ++t) { kv[t] = -INFINITY; ki[t] = 0x7fffffff; }
    const float4* qi4 = (const float4*)qi_s[wv];
    for (int jb = 0; jb < M; jb += 64) {
      int j = jb + lane;
      const float4* qj = (const float4*)(qn + (size_t)j * D);
      float dot = 0.f;
#pragma unroll 8
      for (int ch = 0; ch < 32; ++ch) {
        float4 a = qi4[ch], bq = qj[ch];
        dot += a.x * bq.x + a.y * bq.y + a.z * bq.z + a.w * bq.w;
      }
      topk_insert<KTOP>(kv, ki, dot, j);
    }
#pragma unroll
    for (int off = 1; off < 64; off <<= 1) {
      float pv[KTOP]; int pj[KTOP];
#pragma unroll
      for (int t = 0; t < KTOP; ++t) {
        pv[t] = __shfl_xor(kv[t], off);
        pj[t] = __shfl_xor(ki[t], off);
      }
#pragma unroll
      for (int t = 0; t < KTOP; ++t) topk_insert<KTOP>(kv, ki, pv[t], pj[t]);
    }
  }

  if (lane == 0) {
#pragma unroll
    for (int t = 0; t < KTOP; ++t) {
      kval[(size_t)i * KTOP + t] = kv[t];
      kidx[(size_t)i * KTOP + t] = ki[t];
    }
  }
}

// ---------------------------------------------------------------------------
// k3: mutual mask + softmax over <=9 entries + adapted query + normalize +
// project on normalized prototypes, scale by tao. One wave per query row.
__global__ void k3_out(const float* __restrict__ x, const float* __restrict__ kval,
                       const int* __restrict__ kidx, const float* __restrict__ protnT,
                       const float* __restrict__ taop, float* __restrict__ out) {
  __shared__ float sw[4][KTOP];
  __shared__ int   sj[4][KTOP];
  __shared__ float an[4][D];
  int lane = threadIdx.x & 63;
  int wv   = threadIdx.x >> 6;
  int i = blockIdx.x * 4 + wv;

  float v = -INFINITY; int jt = 0; bool mut = false;
  if (lane < KTOP) {
    v  = kval[(size_t)i * KTOP + lane];
    jt = kidx[(size_t)i * KTOP + lane];
    const int* oj = kidx + (size_t)jt * KTOP;
#pragma unroll
    for (int t = 0; t < KTOP; ++t) mut = mut || (oj[t] == i);
  }
  float lv = mut ? v : -INFINITY;
#pragma unroll
  for (int off = 1; off < 16; off <<= 1) lv = fmaxf(lv, __shfl_xor(lv, off));
  float wexp = mut ? expf(v - lv) : 0.f;    // self is always mutual -> z >= 1
  float z = wexp;
#pragma unroll
  for (int off = 1; off < 16; off <<= 1) z += __shfl_xor(z, off);
  if (lane < KTOP) { sw[wv][lane] = wexp / z; sj[wv][lane] = jt; }
  __syncthreads();

  float a0 = 0.f, a1 = 0.f;
#pragma unroll
  for (int t = 0; t < KTOP; ++t) {
    float wt = sw[wv][t];
    if (wt != 0.f) {
      int j = sj[wv][t];
      int xr = (j >> 7) * XROW + KSHOT + (j & 127);
      const float* qr = x + (size_t)xr * D;
      a0 += wt * qr[lane];
      a1 += wt * qr[64 + lane];
    }
  }
  float ss = a0 * a0 + a1 * a1;
#pragma unroll
  for (int off = 1; off < 64; off <<= 1) ss += __shfl_xor(ss, off);
  float rn = 1.0f / fmaxf(sqrtf(ss), EPSV);
  an[wv][lane]      = a0 * rn;
  an[wv][64 + lane] = a1 * rn;
  __syncthreads();

  float acc = 0.f;
#pragma unroll 8
  for (int d = 0; d < D; ++d) acc += an[wv][d] * protnT[d * NCLS + lane];
  out[(size_t)i * NCLS + lane] = taop[0] * acc;
}

// ---------------------------------------------------------------------------
extern "C" void kernel_launch(void* const* d_in, const int* in_sizes, int n_in,
                              void* d_out, int out_size, void* d_ws, size_t ws_size,
                              hipStream_t stream) {
  const float* x   = (const float*)d_in[0];
  const float* tao = (const float*)d_in[1];
  float* out = (float*)d_out;

  // workspace layout, ~19.5 MB total
  float*    qn     = (float*)d_ws;                    // 8192*128 f32 (4 MB)
  short*    qh     = (short*)(qn + (size_t)M * D);    // 2 MB bf16
  int*      segcnt = (int*)(qh + (size_t)M * D);      // 8192*16 = 512 KB
  unsigned* cand   = (unsigned*)(segcnt + (size_t)M * SJ);  // 12.6 MB packed
  float*    kval   = (float*)(cand + (size_t)M * SJ * CAPB);
  int*      kidx   = (int*)(kval + (size_t)M * KTOP);
  float*    protnT = (float*)(kidx + (size_t)M * KTOP);     // 128*64

  k0_proto<<<NCLS, 64, 0, stream>>>(x, protnT);
  k1_qnorm<<<M / 4, 256, 0, stream>>>(x, qn, qh);
  k2f<<<(M / BI) * SJ, 256, 0, stream>>>(qh, segcnt, cand);
  k_rr<<<M / 4, 256, 0, stream>>>(qn, segcnt, cand, kval, kidx);
  k3_out<<<M / 4, 256, 0, stream>>>(x, kval, kidx, protnT, tao, out);
}

// Round 26
// 96.556 us; speedup vs baseline: 1.1125x; 1.1125x over previous
//
#include <hip/hip_runtime.h>
#include <hip/hip_bf16.h>
#include <math.h>

// Problem constants (N_WAY=64, K_SHOT=5, Q_QUERY=128, D_FEAT=128)
#define M     8192      // n*q query rows
#define D     128       // feature dim
#define NCLS  64        // n classes
#define KSHOT 5
#define XROW  133       // (k+q) rows per class in x
#define KTOP  9
#define EPSV  1e-8f

// Threshold filter + exact certificate (R13) + packed-value segments (R18)
// + bisection select (R19) + 128-i blocks (R20):
//   k2f packs (bf16(v)<<16 | j) for v >= TAU_LO into per-(row,j-split)
//   segments (LDS-counter emission, zero global atomics). k_rr finds the
//   9th-largest STORED value via integer bisection, exact-re-dots only
//   stored >= v9s - 2*EPS_STORE (provable superset of exact top-9:
//   exact9th >= v9s - 0.004(mfma); top-9 member x has stored(x) >= exact(x)
//   - 0.004(mfma) - 0.002(bf16 trunc, sims<1, diag=1.0 exact) >= v9s - 0.010
//   > v9s - 0.012 = th), certifies exact-9th > TAU_LO + EPS_DOT, else inline
//   full-row fallback (P ~ 1e-13/row; do NOT raise TAU_LO -- ~450us, R12).
// R21/R22/R24 lesson (3x confirmed): ANY added live state in k_rr's re-dot
//   loop crosses a 16-VGPR granule (32->48), occupancy 47->31%, and LOSES.
//   k_rr must stay the register-minimal serial v3 body. R25 = R23 body with
//   ONLY the register-free EPS_STORE 0.008->0.006 tightening (~25% fewer
//   serial re-dots).
#define TAU_LO    0.21f
#define EPS_DOT   0.005f
#define EPS_STORE 0.006f    // mfma err 0.004 + bf16 truncation 0.002
#define CAPB      24        // per-(row, j-split) segment capacity (lambda ~4.3)

#define BI    128           // i rows per block in k2f
#define SJ    16
#define JPB   (M / SJ)      // 512 j per block
#define NTIL  (JPB / 16)    // 32 j-tiles of 16
#define NRND  6             // max pair rounds in k_rr (16*24/64 = 6)

typedef __attribute__((__ext_vector_type__(8))) short bf16v8;  // 8 bf16 = 4 VGPR
typedef __attribute__((__ext_vector_type__(4))) float f32v4;

// ---------------------------------------------------------------------------
// register-resident top-K with (value desc, index asc) tie-break, matching
// jax.lax.top_k set semantics; arrival-order independent for distinct indices.
template <int KN>
__device__ __forceinline__ void topk_insert(float (&kv)[KN], int (&ki)[KN],
                                            float v, int j) {
  if (v > kv[KN - 1] || (v == kv[KN - 1] && j < ki[KN - 1])) {
    float cv = v; int cj = j;
#pragma unroll
    for (int t = 0; t < KN; ++t) {
      bool b = (cv > kv[t]) || (cv == kv[t] && cj < ki[t]);
      float tv = kv[t]; int ti_ = ki[t];
      kv[t] = b ? cv : tv;  ki[t] = b ? cj : ti_;
      cv   = b ? tv : cv;   cj   = b ? ti_ : cj;
    }
  }
}

// ---------------------------------------------------------------------------
__global__ void k0_proto(const float* __restrict__ x, float* __restrict__ protnT) {
  int c = blockIdx.x;
  int lane = threadIdx.x;
  const float* base = x + (size_t)(c * XROW) * D;
  float a0 = 0.f, a1 = 0.f;
#pragma unroll
  for (int s = 0; s < KSHOT; ++s) {
    a0 += base[s * D + lane];
    a1 += base[s * D + 64 + lane];
  }
  a0 *= 0.2f; a1 *= 0.2f;
  float ss = a0 * a0 + a1 * a1;
#pragma unroll
  for (int off = 1; off < 64; off <<= 1) ss += __shfl_xor(ss, off);
  float rn = 1.0f / fmaxf(sqrtf(ss), EPSV);
  protnT[lane * NCLS + c]        = a0 * rn;
  protnT[(lane + 64) * NCLS + c] = a1 * rn;
}

// ---------------------------------------------------------------------------
// k1: L2-normalize query rows -> qn (f32) and qh (bf16).
__global__ void k1_qnorm(const float* __restrict__ x, float* __restrict__ qn,
                         short* __restrict__ qh) {
  int lane = threadIdx.x & 63;
  int wv = threadIdx.x >> 6;
  int r = blockIdx.x * 4 + wv;
  int xr = (r >> 7) * XROW + KSHOT + (r & 127);
  const float* src = x + (size_t)xr * D;
  float v0 = src[lane], v1 = src[64 + lane];
  float ss = v0 * v0 + v1 * v1;
#pragma unroll
  for (int off = 1; off < 64; off <<= 1) ss += __shfl_xor(ss, off);
  float rn = 1.0f / fmaxf(sqrtf(ss), EPSV);
  float q0 = v0 * rn, q1 = v1 * rn;
  qn[(size_t)r * D + lane]      = q0;
  qn[(size_t)r * D + 64 + lane] = q1;
  __hip_bfloat16 h0 = __float2bfloat16(q0);
  __hip_bfloat16 h1 = __float2bfloat16(q1);
  qh[(size_t)r * D + lane]      = *(short*)&h0;
  qh[(size_t)r * D + 64 + lane] = *(short*)&h1;
}

// ---------------------------------------------------------------------------
// k2f: bf16 MFMA + threshold filter. LDS-staged double-buffered j-tile,
// 128 i-rows/block (2 i-subs share each A-frag ds_read), LDS per-row
// counters, per-(row, j-split) segments of packed (bf16(v)<<16|j).
// D layout (m89-verified): i-col = lane&15, j-row = (lane>>4)*4 + reg.
// (Frozen since R20.)
__global__ __launch_bounds__(256) void
k2f(const short* __restrict__ qh, int* __restrict__ segcnt,
    unsigned* __restrict__ cand) {
  __shared__ __align__(16) short jh[2][16 * D];   // 2 x 4 KB j-tile
  __shared__ int lcnt[BI];

  const int tid  = threadIdx.x;
  const int l    = tid & 63;
  const int w    = tid >> 6;
  const int ib   = blockIdx.x >> 4;        // 64 i-strips of 128
  const int js   = blockIdx.x & (SJ - 1);  // 16 j-splits
  const int i0   = ib * BI;
  const int j0s  = js * JPB;

  if (tid < BI) lcnt[tid] = 0;

  const bf16v8* qh8 = (const bf16v8*)qh;
  const int lg   = l >> 4;                 // k-group 0..3
  const int arow = l & 15;
  const int lrow = w * 16 + arow;          // local row 0..63 (i-sub 0)
  const int myi  = i0 + lrow;              // i-sub 0 row
  const int myi2 = myi + 64;               // i-sub 1 row

  bf16v8 bh[4], bg[4];
#pragma unroll
  for (int kk = 0; kk < 4; ++kk) {
    bh[kk] = qh8[(size_t)myi  * 16 + kk * 4 + lg];
    bg[kk] = qh8[(size_t)myi2 * 16 + kk * 4 + lg];
  }

  const int srow = tid >> 4;
  const int schk = tid & 15;
  const int sslot = srow * 16 + (schk ^ (srow & 7));
  int rslot[4];
#pragma unroll
  for (int kk = 0; kk < 4; ++kk)
    rslot[kk] = arow * 16 + ((kk * 4 + lg) ^ (arow & 7));

  unsigned* seg  = cand + ((size_t)myi  * SJ + js) * CAPB;
  unsigned* seg2 = cand + ((size_t)myi2 * SJ + js) * CAPB;

  bf16v8 sa = qh8[(size_t)(j0s + srow) * 16 + schk];
  ((bf16v8*)jh[0])[sslot] = sa;
  sa = qh8[(size_t)(j0s + 16 + srow) * 16 + schk];
  __syncthreads();                         // covers lcnt init + buf0

  for (int t = 0; t < NTIL; ++t) {
    if (t + 1 < NTIL) {
      ((bf16v8*)jh[(t + 1) & 1])[sslot] = sa;
      if (t + 2 < NTIL)
        sa = qh8[(size_t)(j0s + (t + 2) * 16 + srow) * 16 + schk];
    }

    const bf16v8* H = (const bf16v8*)jh[t & 1];
    f32v4 a0 = {0.f, 0.f, 0.f, 0.f};
    f32v4 a1 = {0.f, 0.f, 0.f, 0.f};
    f32v4 c0 = {0.f, 0.f, 0.f, 0.f};
    f32v4 c1 = {0.f, 0.f, 0.f, 0.f};
#pragma unroll
    for (int kk = 0; kk < 4; ++kk) {
      bf16v8 ah = H[rslot[kk]];            // one ds_read feeds both i-subs
      if (kk & 1) {
        a1 = __builtin_amdgcn_mfma_f32_16x16x32_bf16(ah, bh[kk], a1, 0, 0, 0);
        c1 = __builtin_amdgcn_mfma_f32_16x16x32_bf16(ah, bg[kk], c1, 0, 0, 0);
      } else {
        a0 = __builtin_amdgcn_mfma_f32_16x16x32_bf16(ah, bh[kk], a0, 0, 0, 0);
        c0 = __builtin_amdgcn_mfma_f32_16x16x32_bf16(ah, bg[kk], c0, 0, 0, 0);
      }
    }
    f32v4 s = a0 + a1;
    f32v4 r2 = c0 + c1;

    const int jb = j0s + t * 16 + lg * 4;
#pragma unroll
    for (int u = 0; u < 4; ++u) {
      if (s[u] >= TAU_LO) {                // ~0.9% of values
        int slot = atomicAdd(&lcnt[lrow], 1);
        if (slot < CAPB)
          seg[slot] = (__float_as_uint(s[u]) & 0xFFFF0000u) | (unsigned)(jb + u);
      }
      if (r2[u] >= TAU_LO) {
        int slot = atomicAdd(&lcnt[lrow + 64], 1);
        if (slot < CAPB)
          seg2[slot] = (__float_as_uint(r2[u]) & 0xFFFF0000u) | (unsigned)(jb + u);
      }
    }

    __syncthreads();
  }

  if (tid < BI)
    segcnt[(size_t)(i0 + tid) * SJ + js] = lcnt[tid];
}

// ---------------------------------------------------------------------------
// k_rr (R23 v6 body, byte-identical structure): serial re-dot, register-
// minimal (VGPR 32, occ 47%); dead-round skip + 9-step bisection.
__global__ void k_rr(const float* __restrict__ qn, const int* __restrict__ segcnt,
                     const unsigned* __restrict__ cand,
                     float* __restrict__ kval, int* __restrict__ kidx) {
  __shared__ float qi_s[4][D];
  int lane = threadIdx.x & 63;
  int wv   = threadIdx.x >> 6;
  int i = blockIdx.x * 4 + wv;

  float qi0 = qn[(size_t)i * D + lane];
  float qi1 = qn[(size_t)i * D + 64 + lane];

  // --- segment counts + prefix scan (lanes 0..15) ---
  int sc = (lane < SJ) ? segcnt[(size_t)i * SJ + lane] : 0;
  bool bad = __any(lane < SJ && sc > CAPB);
  int pre = sc;
#pragma unroll
  for (int off = 1; off < 16; off <<= 1) {
    int o = __shfl_up(pre, off, 16);
    if ((lane & 15) >= off) pre += o;
  }
  int b[SJ];                               // inclusive prefix, all lanes
#pragma unroll
  for (int k = 0; k < SJ; ++k) b[k] = __shfl(pre, k);
  const int ct = b[SJ - 1];
  bad = bad || (ct < KTOP);
  const int nra = (ct + 63) >> 6;          // active rounds, wave-uniform

  // --- lane-parallel packed-pair load (dead rounds skipped, NO inserts) ---
  const unsigned* crow = cand + (size_t)i * SJ * CAPB;
  float vv[NRND]; int jj[NRND];
#pragma unroll
  for (int r = 0; r < NRND; ++r) {
    vv[r] = 0.f; jj[r] = 0;
    if (r < nra) {                         // wave-uniform guard, static index
      int t = r * 64 + lane;
      bool valid = t < ct;
      int s = 0, off = 0;
#pragma unroll
      for (int k = 0; k < SJ; ++k) {       // b nondecreasing -> cmov scan
        bool ge = t >= b[k];
        s   = ge ? k + 1 : s;
        off = ge ? b[k] : off;
      }
      unsigned u = valid ? crow[s * CAPB + (t - off)] : 0u;
      vv[r] = __uint_as_float(u & 0xFFFF0000u);  // exact bf16 payload (>=0)
      jj[r] = (int)(u & 8191u);
    }
  }

  // --- bisect 9th-largest stored value; stored in [bf16(0.21)=0x3E57, ~0x3F81]
  //     so [0x3E00, 0x3FFF] covers it; ct>=9 keeps the invariant at lo ---
  int lo = 0x3E00, hi = 0x3FFF;
  while (lo < hi) {                        // 9 uniform iterations
    int mid = (lo + hi + 1) >> 1;
    unsigned um = (unsigned)mid << 16;
    int cnt = 0;
#pragma unroll
    for (int r = 0; r < NRND; ++r)
      if (r < nra)
        cnt += (int)__popcll(__ballot(__float_as_uint(vv[r]) >= um));
    if (cnt >= KTOP) lo = mid; else hi = mid - 1;
  }
  const float th = __uint_as_float((unsigned)lo << 16) - 2.0f * EPS_STORE;

  // --- serial exact re-dot of the borderline set (~10/row; R19 v3 form) ---
  float kv[KTOP]; int ki[KTOP];
#pragma unroll
  for (int t = 0; t < KTOP; ++t) { kv[t] = -INFINITY; ki[t] = 0x7fffffff; }
  if (!bad) {
#pragma unroll
    for (int r = 0; r < NRND; ++r) {
      if (r >= nra) continue;              // wave-uniform
      unsigned long long mask = __ballot(vv[r] >= th);   // invalids are 0 < th
      while (mask) {
        int bl = (int)__ffsll((long long)mask) - 1;
        mask &= mask - 1;
        int jc = __shfl(jj[r], bl);        // wave-uniform
        float p = qi0 * qn[(size_t)jc * D + lane] +
                  qi1 * qn[(size_t)jc * D + 64 + lane];
#pragma unroll
        for (int off = 1; off < 64; off <<= 1) p += __shfl_xor(p, off);
        topk_insert<KTOP>(kv, ki, p, jc);
      }
    }
  }

  // --- certificate; else inline exact full-row fallback ---
  if (bad || kv[KTOP - 1] <= TAU_LO + EPS_DOT) {
    qi_s[wv][lane]      = qi0;
    qi_s[wv][64 + lane] = qi1;
#pragma unroll
    for (int t = 0; t < KTOP; ++t) { kv[t] = -INFINITY; ki[t] = 0x7fffffff; }
    const float4* qi4 = (const float4*)qi_s[wv];
    for (int jb = 0; jb < M; jb += 64) {
      int j = jb + lane;
      const float4* qj = (const float4*)(qn + (size_t)j * D);
      float dot = 0.f;
#pragma unroll 8
      for (int ch = 0; ch < 32; ++ch) {
        float4 a = qi4[ch], bq = qj[ch];
        dot += a.x * bq.x + a.y * bq.y + a.z * bq.z + a.w * bq.w;
      }
      topk_insert<KTOP>(kv, ki, dot, j);
    }
#pragma unroll
    for (int off = 1; off < 64; off <<= 1) {
      float pv[KTOP]; int pj[KTOP];
#pragma unroll
      for (int t = 0; t < KTOP; ++t) {
        pv[t] = __shfl_xor(kv[t], off);
        pj[t] = __shfl_xor(ki[t], off);
      }
#pragma unroll
      for (int t = 0; t < KTOP; ++t) topk_insert<KTOP>(kv, ki, pv[t], pj[t]);
    }
  }

  if (lane == 0) {
#pragma unroll
    for (int t = 0; t < KTOP; ++t) {
      kval[(size_t)i * KTOP + t] = kv[t];
      kidx[(size_t)i * KTOP + t] = ki[t];
    }
  }
}

// ---------------------------------------------------------------------------
// k3: mutual mask + softmax over <=9 entries + adapted query + normalize +
// project on normalized prototypes, scale by tao. One wave per query row.
__global__ void k3_out(const float* __restrict__ x, const float* __restrict__ kval,
                       const int* __restrict__ kidx, const float* __restrict__ protnT,
                       const float* __restrict__ taop, float* __restrict__ out) {
  __shared__ float sw[4][KTOP];
  __shared__ int   sj[4][KTOP];
  __shared__ float an[4][D];
  int lane = threadIdx.x & 63;
  int wv   = threadIdx.x >> 6;
  int i = blockIdx.x * 4 + wv;

  float v = -INFINITY; int jt = 0; bool mut = false;
  if (lane < KTOP) {
    v  = kval[(size_t)i * KTOP + lane];
    jt = kidx[(size_t)i * KTOP + lane];
    const int* oj = kidx + (size_t)jt * KTOP;
#pragma unroll
    for (int t = 0; t < KTOP; ++t) mut = mut || (oj[t] == i);
  }
  float lv = mut ? v : -INFINITY;
#pragma unroll
  for (int off = 1; off < 16; off <<= 1) lv = fmaxf(lv, __shfl_xor(lv, off));
  float wexp = mut ? expf(v - lv) : 0.f;    // self is always mutual -> z >= 1
  float z = wexp;
#pragma unroll
  for (int off = 1; off < 16; off <<= 1) z += __shfl_xor(z, off);
  if (lane < KTOP) { sw[wv][lane] = wexp / z; sj[wv][lane] = jt; }
  __syncthreads();

  float a0 = 0.f, a1 = 0.f;
#pragma unroll
  for (int t = 0; t < KTOP; ++t) {
    float wt = sw[wv][t];
    if (wt != 0.f) {
      int j = sj[wv][t];
      int xr = (j >> 7) * XROW + KSHOT + (j & 127);
      const float* qr = x + (size_t)xr * D;
      a0 += wt * qr[lane];
      a1 += wt * qr[64 + lane];
    }
  }
  float ss = a0 * a0 + a1 * a1;
#pragma unroll
  for (int off = 1; off < 64; off <<= 1) ss += __shfl_xor(ss, off);
  float rn = 1.0f / fmaxf(sqrtf(ss), EPSV);
  an[wv][lane]      = a0 * rn;
  an[wv][64 + lane] = a1 * rn;
  __syncthreads();

  float acc = 0.f;
#pragma unroll 8
  for (int d = 0; d < D; ++d) acc += an[wv][d] * protnT[d * NCLS + lane];
  out[(size_t)i * NCLS + lane] = taop[0] * acc;
}

// ---------------------------------------------------------------------------
extern "C" void kernel_launch(void* const* d_in, const int* in_sizes, int n_in,
                              void* d_out, int out_size, void* d_ws, size_t ws_size,
                              hipStream_t stream) {
  const float* x   = (const float*)d_in[0];
  const float* tao = (const float*)d_in[1];
  float* out = (float*)d_out;

  // workspace layout, ~19.5 MB total
  float*    qn     = (float*)d_ws;                    // 8192*128 f32 (4 MB)
  short*    qh     = (short*)(qn + (size_t)M * D);    // 2 MB bf16
  int*      segcnt = (int*)(qh + (size_t)M * D);      // 8192*16 = 512 KB
  unsigned* cand   = (unsigned*)(segcnt + (size_t)M * SJ);  // 12.6 MB packed
  float*    kval   = (float*)(cand + (size_t)M * SJ * CAPB);
  int*      kidx   = (int*)(kval + (size_t)M * KTOP);
  float*    protnT = (float*)(kidx + (size_t)M * KTOP);     // 128*64

  k0_proto<<<NCLS, 64, 0, stream>>>(x, protnT);
  k1_qnorm<<<M / 4, 256, 0, stream>>>(x, qn, qh);
  k2f<<<(M / BI) * SJ, 256, 0, stream>>>(qh, segcnt, cand);
  k_rr<<<M / 4, 256, 0, stream>>>(qn, segcnt, cand, kval, kidx);
  k3_out<<<M / 4, 256, 0, stream>>>(x, kval, kidx, protnT, tao, out);
}

// Round 27
// 93.009 us; speedup vs baseline: 1.1549x; 1.0381x over previous
//
#include <hip/hip_runtime.h>
#include <hip/hip_bf16.h>
#include <math.h>

// Problem constants (N_WAY=64, K_SHOT=5, Q_QUERY=128, D_FEAT=128)
#define M     8192      // n*q query rows
#define D     128       // feature dim
#define NCLS  64        // n classes
#define KSHOT 5
#define XROW  133       // (k+q) rows per class in x
#define KTOP  9
#define EPSV  1e-8f

// Threshold filter + exact certificate (R13) + packed-value segments (R18)
// + bisection select (R19) + 128-i blocks (R20) + EPS tightening (R25)
// + k0/k1 fusion (R26, dispatch-count 5 -> 4):
//   k2f packs (bf16(v)<<16 | j) for v >= TAU_LO into per-(row,j-split)
//   segments (LDS-counter emission, zero global atomics). k_rr finds the
//   9th-largest STORED value via integer bisection, exact-re-dots only
//   stored >= v9s - 2*EPS_STORE (provable superset of exact top-9:
//   exact9th >= v9s - 0.004(mfma); top-9 member x has stored(x) >= exact(x)
//   - 0.004(mfma) - 0.002(bf16 trunc, sims<1, diag=1.0 exact) >= v9s - 0.010
//   > v9s - 0.012 = th), certifies exact-9th > TAU_LO + EPS_DOT, else inline
//   full-row fallback (P ~ 1e-13/row; do NOT raise TAU_LO -- ~450us, R12).
// R21/R22/R24 lesson (3x confirmed): ANY added live state in k_rr's re-dot
//   loop crosses a 16-VGPR granule (32->48), occupancy 47->31%, and LOSES.
//   k_rr stays the register-minimal serial v3 body.
#define TAU_LO    0.21f
#define EPS_DOT   0.005f
#define EPS_STORE 0.006f    // mfma err 0.004 + bf16 truncation 0.002
#define CAPB      24        // per-(row, j-split) segment capacity (lambda ~4.3)

#define BI    128           // i rows per block in k2f
#define SJ    16
#define JPB   (M / SJ)      // 512 j per block
#define NTIL  (JPB / 16)    // 32 j-tiles of 16
#define NRND  6             // max pair rounds in k_rr (16*24/64 = 6)
#define K1BLK (M / 4)       // qnorm blocks in fused k1 (2048)

typedef __attribute__((__ext_vector_type__(8))) short bf16v8;  // 8 bf16 = 4 VGPR
typedef __attribute__((__ext_vector_type__(4))) float f32v4;

// ---------------------------------------------------------------------------
// register-resident top-K with (value desc, index asc) tie-break, matching
// jax.lax.top_k set semantics; arrival-order independent for distinct indices.
template <int KN>
__device__ __forceinline__ void topk_insert(float (&kv)[KN], int (&ki)[KN],
                                            float v, int j) {
  if (v > kv[KN - 1] || (v == kv[KN - 1] && j < ki[KN - 1])) {
    float cv = v; int cj = j;
#pragma unroll
    for (int t = 0; t < KN; ++t) {
      bool b = (cv > kv[t]) || (cv == kv[t] && cj < ki[t]);
      float tv = kv[t]; int ti_ = ki[t];
      kv[t] = b ? cv : tv;  ki[t] = b ? cj : ti_;
      cv   = b ? tv : cv;   cj   = b ? ti_ : cj;
    }
  }
}

// ---------------------------------------------------------------------------
// k1f (fused): blocks [0, K1BLK) L2-normalize query rows -> qn (f32) + qh
// (bf16); blocks [K1BLK, K1BLK+16) compute the 64 class prototypes
// (4 classes/block, one wave per class), L2-normalized, stored TRANSPOSED
// protnT[d][c] so k3's per-lane-class reads are coalesced.
__global__ void k1f(const float* __restrict__ x, float* __restrict__ qn,
                    short* __restrict__ qh, float* __restrict__ protnT) {
  int lane = threadIdx.x & 63;
  int wv   = threadIdx.x >> 6;
  int blk  = blockIdx.x;

  if (blk < K1BLK) {                       // ---- qnorm path (R25 k1 body) ----
    int r = blk * 4 + wv;
    int xr = (r >> 7) * XROW + KSHOT + (r & 127);
    const float* src = x + (size_t)xr * D;
    float v0 = src[lane], v1 = src[64 + lane];
    float ss = v0 * v0 + v1 * v1;
#pragma unroll
    for (int off = 1; off < 64; off <<= 1) ss += __shfl_xor(ss, off);
    float rn = 1.0f / fmaxf(sqrtf(ss), EPSV);
    float q0 = v0 * rn, q1 = v1 * rn;
    qn[(size_t)r * D + lane]      = q0;
    qn[(size_t)r * D + 64 + lane] = q1;
    __hip_bfloat16 h0 = __float2bfloat16(q0);
    __hip_bfloat16 h1 = __float2bfloat16(q1);
    qh[(size_t)r * D + lane]      = *(short*)&h0;
    qh[(size_t)r * D + 64 + lane] = *(short*)&h1;
  } else {                                 // ---- proto path (R25 k0 body) ----
    int c = (blk - K1BLK) * 4 + wv;        // class 0..63
    const float* base = x + (size_t)(c * XROW) * D;
    float a0 = 0.f, a1 = 0.f;
#pragma unroll
    for (int s = 0; s < KSHOT; ++s) {
      a0 += base[s * D + lane];
      a1 += base[s * D + 64 + lane];
    }
    a0 *= 0.2f; a1 *= 0.2f;
    float ss = a0 * a0 + a1 * a1;
#pragma unroll
    for (int off = 1; off < 64; off <<= 1) ss += __shfl_xor(ss, off);
    float rn = 1.0f / fmaxf(sqrtf(ss), EPSV);
    protnT[lane * NCLS + c]        = a0 * rn;
    protnT[(lane + 64) * NCLS + c] = a1 * rn;
  }
}

// ---------------------------------------------------------------------------
// k2f: bf16 MFMA + threshold filter. LDS-staged double-buffered j-tile,
// 128 i-rows/block (2 i-subs share each A-frag ds_read), LDS per-row
// counters, per-(row, j-split) segments of packed (bf16(v)<<16|j).
// D layout (m89-verified): i-col = lane&15, j-row = (lane>>4)*4 + reg.
// (Frozen since R20.)
__global__ __launch_bounds__(256) void
k2f(const short* __restrict__ qh, int* __restrict__ segcnt,
    unsigned* __restrict__ cand) {
  __shared__ __align__(16) short jh[2][16 * D];   // 2 x 4 KB j-tile
  __shared__ int lcnt[BI];

  const int tid  = threadIdx.x;
  const int l    = tid & 63;
  const int w    = tid >> 6;
  const int ib   = blockIdx.x >> 4;        // 64 i-strips of 128
  const int js   = blockIdx.x & (SJ - 1);  // 16 j-splits
  const int i0   = ib * BI;
  const int j0s  = js * JPB;

  if (tid < BI) lcnt[tid] = 0;

  const bf16v8* qh8 = (const bf16v8*)qh;
  const int lg   = l >> 4;                 // k-group 0..3
  const int arow = l & 15;
  const int lrow = w * 16 + arow;          // local row 0..63 (i-sub 0)
  const int myi  = i0 + lrow;              // i-sub 0 row
  const int myi2 = myi + 64;               // i-sub 1 row

  bf16v8 bh[4], bg[4];
#pragma unroll
  for (int kk = 0; kk < 4; ++kk) {
    bh[kk] = qh8[(size_t)myi  * 16 + kk * 4 + lg];
    bg[kk] = qh8[(size_t)myi2 * 16 + kk * 4 + lg];
  }

  const int srow = tid >> 4;
  const int schk = tid & 15;
  const int sslot = srow * 16 + (schk ^ (srow & 7));
  int rslot[4];
#pragma unroll
  for (int kk = 0; kk < 4; ++kk)
    rslot[kk] = arow * 16 + ((kk * 4 + lg) ^ (arow & 7));

  unsigned* seg  = cand + ((size_t)myi  * SJ + js) * CAPB;
  unsigned* seg2 = cand + ((size_t)myi2 * SJ + js) * CAPB;

  bf16v8 sa = qh8[(size_t)(j0s + srow) * 16 + schk];
  ((bf16v8*)jh[0])[sslot] = sa;
  sa = qh8[(size_t)(j0s + 16 + srow) * 16 + schk];
  __syncthreads();                         // covers lcnt init + buf0

  for (int t = 0; t < NTIL; ++t) {
    if (t + 1 < NTIL) {
      ((bf16v8*)jh[(t + 1) & 1])[sslot] = sa;
      if (t + 2 < NTIL)
        sa = qh8[(size_t)(j0s + (t + 2) * 16 + srow) * 16 + schk];
    }

    const bf16v8* H = (const bf16v8*)jh[t & 1];
    f32v4 a0 = {0.f, 0.f, 0.f, 0.f};
    f32v4 a1 = {0.f, 0.f, 0.f, 0.f};
    f32v4 c0 = {0.f, 0.f, 0.f, 0.f};
    f32v4 c1 = {0.f, 0.f, 0.f, 0.f};
#pragma unroll
    for (int kk = 0; kk < 4; ++kk) {
      bf16v8 ah = H[rslot[kk]];            // one ds_read feeds both i-subs
      if (kk & 1) {
        a1 = __builtin_amdgcn_mfma_f32_16x16x32_bf16(ah, bh[kk], a1, 0, 0, 0);
        c1 = __builtin_amdgcn_mfma_f32_16x16x32_bf16(ah, bg[kk], c1, 0, 0, 0);
      } else {
        a0 = __builtin_amdgcn_mfma_f32_16x16x32_bf16(ah, bh[kk], a0, 0, 0, 0);
        c0 = __builtin_amdgcn_mfma_f32_16x16x32_bf16(ah, bg[kk], c0, 0, 0, 0);
      }
    }
    f32v4 s = a0 + a1;
    f32v4 r2 = c0 + c1;

    const int jb = j0s + t * 16 + lg * 4;
#pragma unroll
    for (int u = 0; u < 4; ++u) {
      if (s[u] >= TAU_LO) {                // ~0.9% of values
        int slot = atomicAdd(&lcnt[lrow], 1);
        if (slot < CAPB)
          seg[slot] = (__float_as_uint(s[u]) & 0xFFFF0000u) | (unsigned)(jb + u);
      }
      if (r2[u] >= TAU_LO) {
        int slot = atomicAdd(&lcnt[lrow + 64], 1);
        if (slot < CAPB)
          seg2[slot] = (__float_as_uint(r2[u]) & 0xFFFF0000u) | (unsigned)(jb + u);
      }
    }

    __syncthreads();
  }

  if (tid < BI)
    segcnt[(size_t)(i0 + tid) * SJ + js] = lcnt[tid];
}

// ---------------------------------------------------------------------------
// k_rr (R23/R25 body): serial re-dot, register-minimal (VGPR 32, occ 47%);
// dead-round skip + 9-step bisection.
__global__ void k_rr(const float* __restrict__ qn, const int* __restrict__ segcnt,
                     const unsigned* __restrict__ cand,
                     float* __restrict__ kval, int* __restrict__ kidx) {
  __shared__ float qi_s[4][D];
  int lane = threadIdx.x & 63;
  int wv   = threadIdx.x >> 6;
  int i = blockIdx.x * 4 + wv;

  float qi0 = qn[(size_t)i * D + lane];
  float qi1 = qn[(size_t)i * D + 64 + lane];

  // --- segment counts + prefix scan (lanes 0..15) ---
  int sc = (lane < SJ) ? segcnt[(size_t)i * SJ + lane] : 0;
  bool bad = __any(lane < SJ && sc > CAPB);
  int pre = sc;
#pragma unroll
  for (int off = 1; off < 16; off <<= 1) {
    int o = __shfl_up(pre, off, 16);
    if ((lane & 15) >= off) pre += o;
  }
  int b[SJ];                               // inclusive prefix, all lanes
#pragma unroll
  for (int k = 0; k < SJ; ++k) b[k] = __shfl(pre, k);
  const int ct = b[SJ - 1];
  bad = bad || (ct < KTOP);
  const int nra = (ct + 63) >> 6;          // active rounds, wave-uniform

  // --- lane-parallel packed-pair load (dead rounds skipped, NO inserts) ---
  const unsigned* crow = cand + (size_t)i * SJ * CAPB;
  float vv[NRND]; int jj[NRND];
#pragma unroll
  for (int r = 0; r < NRND; ++r) {
    vv[r] = 0.f; jj[r] = 0;
    if (r < nra) {                         // wave-uniform guard, static index
      int t = r * 64 + lane;
      bool valid = t < ct;
      int s = 0, off = 0;
#pragma unroll
      for (int k = 0; k < SJ; ++k) {       // b nondecreasing -> cmov scan
        bool ge = t >= b[k];
        s   = ge ? k + 1 : s;
        off = ge ? b[k] : off;
      }
      unsigned u = valid ? crow[s * CAPB + (t - off)] : 0u;
      vv[r] = __uint_as_float(u & 0xFFFF0000u);  // exact bf16 payload (>=0)
      jj[r] = (int)(u & 8191u);
    }
  }

  // --- bisect 9th-largest stored value; stored in [bf16(0.21)=0x3E57, ~0x3F81]
  //     so [0x3E00, 0x3FFF] covers it; ct>=9 keeps the invariant at lo ---
  int lo = 0x3E00, hi = 0x3FFF;
  while (lo < hi) {                        // 9 uniform iterations
    int mid = (lo + hi + 1) >> 1;
    unsigned um = (unsigned)mid << 16;
    int cnt = 0;
#pragma unroll
    for (int r = 0; r < NRND; ++r)
      if (r < nra)
        cnt += (int)__popcll(__ballot(__float_as_uint(vv[r]) >= um));
    if (cnt >= KTOP) lo = mid; else hi = mid - 1;
  }
  const float th = __uint_as_float((unsigned)lo << 16) - 2.0f * EPS_STORE;

  // --- serial exact re-dot of the borderline set (~10/row; R19 v3 form) ---
  float kv[KTOP]; int ki[KTOP];
#pragma unroll
  for (int t = 0; t < KTOP; ++t) { kv[t] = -INFINITY; ki[t] = 0x7fffffff; }
  if (!bad) {
#pragma unroll
    for (int r = 0; r < NRND; ++r) {
      if (r >= nra) continue;              // wave-uniform
      unsigned long long mask = __ballot(vv[r] >= th);   // invalids are 0 < th
      while (mask) {
        int bl = (int)__ffsll((long long)mask) - 1;
        mask &= mask - 1;
        int jc = __shfl(jj[r], bl);        // wave-uniform
        float p = qi0 * qn[(size_t)jc * D + lane] +
                  qi1 * qn[(size_t)jc * D + 64 + lane];
#pragma unroll
        for (int off = 1; off < 64; off <<= 1) p += __shfl_xor(p, off);
        topk_insert<KTOP>(kv, ki, p, jc);
      }
    }
  }

  // --- certificate; else inline exact full-row fallback ---
  if (bad || kv[KTOP - 1] <= TAU_LO + EPS_DOT) {
    qi_s[wv][lane]      = qi0;
    qi_s[wv][64 + lane] = qi1;
#pragma unroll
    for (int t = 0; t < KTOP; ++t) { kv[t] = -INFINITY; ki[t] = 0x7fffffff; }
    const float4* qi4 = (const float4*)qi_s[wv];
    for (int jb = 0; jb < M; jb += 64) {
      int j = jb + lane;
      const float4* qj = (const float4*)(qn + (size_t)j * D);
      float dot = 0.f;
#pragma unroll 8
      for (int ch = 0; ch < 32; ++ch) {
        float4 a = qi4[ch], bq = qj[ch];
        dot += a.x * bq.x + a.y * bq.y + a.z * bq.z + a.w * bq.w;
      }
      topk_insert<KTOP>(kv, ki, dot, j);
    }
#pragma unroll
    for (int off = 1; off < 64; off <<= 1) {
      float pv[KTOP]; int pj[KTOP];
#pragma unroll
      for (int t = 0; t < KTOP; ++t) {
        pv[t] = __shfl_xor(kv[t], off);
        pj[t] = __shfl_xor(ki[t], off);
      }
#pragma unroll
      for (int t = 0; t < KTOP; ++t) topk_insert<KTOP>(kv, ki, pv[t], pj[t]);
    }
  }

  if (lane == 0) {
#pragma unroll
    for (int t = 0; t < KTOP; ++t) {
      kval[(size_t)i * KTOP + t] = kv[t];
      kidx[(size_t)i * KTOP + t] = ki[t];
    }
  }
}

// ---------------------------------------------------------------------------
// k3: mutual mask + softmax over <=9 entries + adapted query + normalize +
// project on normalized prototypes, scale by tao. One wave per query row.
__global__ void k3_out(const float* __restrict__ x, const float* __restrict__ kval,
                       const int* __restrict__ kidx, const float* __restrict__ protnT,
                       const float* __restrict__ taop, float* __restrict__ out) {
  __shared__ float sw[4][KTOP];
  __shared__ int   sj[4][KTOP];
  __shared__ float an[4][D];
  int lane = threadIdx.x & 63;
  int wv   = threadIdx.x >> 6;
  int i = blockIdx.x * 4 + wv;

  float v = -INFINITY; int jt = 0; bool mut = false;
  if (lane < KTOP) {
    v  = kval[(size_t)i * KTOP + lane];
    jt = kidx[(size_t)i * KTOP + lane];
    const int* oj = kidx + (size_t)jt * KTOP;
#pragma unroll
    for (int t = 0; t < KTOP; ++t) mut = mut || (oj[t] == i);
  }
  float lv = mut ? v : -INFINITY;
#pragma unroll
  for (int off = 1; off < 16; off <<= 1) lv = fmaxf(lv, __shfl_xor(lv, off));
  float wexp = mut ? expf(v - lv) : 0.f;    // self is always mutual -> z >= 1
  float z = wexp;
#pragma unroll
  for (int off = 1; off < 16; off <<= 1) z += __shfl_xor(z, off);
  if (lane < KTOP) { sw[wv][lane] = wexp / z; sj[wv][lane] = jt; }
  __syncthreads();

  float a0 = 0.f, a1 = 0.f;
#pragma unroll
  for (int t = 0; t < KTOP; ++t) {
    float wt = sw[wv][t];
    if (wt != 0.f) {
      int j = sj[wv][t];
      int xr = (j >> 7) * XROW + KSHOT + (j & 127);
      const float* qr = x + (size_t)xr * D;
      a0 += wt * qr[lane];
      a1 += wt * qr[64 + lane];
    }
  }
  float ss = a0 * a0 + a1 * a1;
#pragma unroll
  for (int off = 1; off < 64; off <<= 1) ss += __shfl_xor(ss, off);
  float rn = 1.0f / fmaxf(sqrtf(ss), EPSV);
  an[wv][lane]      = a0 * rn;
  an[wv][64 + lane] = a1 * rn;
  __syncthreads();

  float acc = 0.f;
#pragma unroll 8
  for (int d = 0; d < D; ++d) acc += an[wv][d] * protnT[d * NCLS + lane];
  out[(size_t)i * NCLS + lane] = taop[0] * acc;
}

// ---------------------------------------------------------------------------
extern "C" void kernel_launch(void* const* d_in, const int* in_sizes, int n_in,
                              void* d_out, int out_size, void* d_ws, size_t ws_size,
                              hipStream_t stream) {
  const float* x   = (const float*)d_in[0];
  const float* tao = (const float*)d_in[1];
  float* out = (float*)d_out;

  // workspace layout, ~19.5 MB total
  float*    qn     = (float*)d_ws;                    // 8192*128 f32 (4 MB)
  short*    qh     = (short*)(qn + (size_t)M * D);    // 2 MB bf16
  int*      segcnt = (int*)(qh + (size_t)M * D);      // 8192*16 = 512 KB
  unsigned* cand   = (unsigned*)(segcnt + (size_t)M * SJ);  // 12.6 MB packed
  float*    kval   = (float*)(cand + (size_t)M * SJ * CAPB);
  int*      kidx   = (int*)(kval + (size_t)M * KTOP);
  float*    protnT = (float*)(kidx + (size_t)M * KTOP);     // 128*64

  k1f<<<K1BLK + NCLS / 4, 256, 0, stream>>>(x, qn, qh, protnT);
  k2f<<<(M / BI) * SJ, 256, 0, stream>>>(qh, segcnt, cand);
  k_rr<<<M / 4, 256, 0, stream>>>(qn, segcnt, cand, kval, kidx);
  k3_out<<<M / 4, 256, 0, stream>>>(x, kval, kidx, protnT, tao, out);
}

// Round 28
// 92.924 us; speedup vs baseline: 1.1560x; 1.0009x over previous
//
#include <hip/hip_runtime.h>
#include <hip/hip_bf16.h>
#include <math.h>

// Problem constants (N_WAY=64, K_SHOT=5, Q_QUERY=128, D_FEAT=128)
#define M     8192      // n*q query rows
#define D     128       // feature dim
#define NCLS  64        // n classes
#define KSHOT 5
#define XROW  133       // (k+q) rows per class in x
#define KTOP  9
#define EPSV  1e-8f

// Threshold filter + exact certificate (R13) + packed-value segments (R18)
// + bisection select (R19) + EPS tightening (R25) + k0/k1 fusion (R26)
// + 256-i / 8-wave k2f blocks (R27):
//   k2f packs (bf16(v)<<16 | j) for v >= TAU_LO into per-(row,j-split)
//   segments (LDS-counter emission, zero global atomics). k_rr finds the
//   9th-largest STORED value via integer bisection, exact-re-dots only
//   stored >= v9s - 2*EPS_STORE (provable superset of exact top-9:
//   exact9th >= v9s - 0.004(mfma); top-9 member x has stored(x) >= exact(x)
//   - 0.004(mfma) - 0.002(bf16 trunc, sims<1, diag=1.0 exact) >= v9s - 0.010
//   > v9s - 0.012 = th), certifies exact-9th > TAU_LO + EPS_DOT, else inline
//   full-row fallback (P ~ 1e-13/row; do NOT raise TAU_LO -- ~450us, R12).
// R21/R22/R24 lesson (3x confirmed): ANY added live state in k_rr's re-dot
//   loop crosses a 16-VGPR granule (32->48), occupancy 47->31%, and LOSES.
//   k_rr stays the register-minimal serial v3 body.
// R27: k2f widened to 512 thr / BI=256 (R20's amortization lever, register-
//   neutral: each wave still holds 2 i-sub fragment sets). Tile-stage +
//   barrier count per MFMA halves; occupancy unchanged (2 blk/CU x 8 waves).
#define TAU_LO    0.21f
#define EPS_DOT   0.005f
#define EPS_STORE 0.006f    // mfma err 0.004 + bf16 truncation 0.002
#define CAPB      24        // per-(row, j-split) segment capacity (lambda ~4.3)

#define BI    256           // i rows per block in k2f (8 waves x 2 i-subs x 16)
#define SJ    16
#define JPB   (M / SJ)      // 512 j per block
#define NTIL  (JPB / 16)    // 32 j-tiles of 16
#define NRND  6             // max pair rounds in k_rr (16*24/64 = 6)
#define K1BLK (M / 4)       // qnorm blocks in fused k1 (2048)

typedef __attribute__((__ext_vector_type__(8))) short bf16v8;  // 8 bf16 = 4 VGPR
typedef __attribute__((__ext_vector_type__(4))) float f32v4;

// ---------------------------------------------------------------------------
// register-resident top-K with (value desc, index asc) tie-break, matching
// jax.lax.top_k set semantics; arrival-order independent for distinct indices.
template <int KN>
__device__ __forceinline__ void topk_insert(float (&kv)[KN], int (&ki)[KN],
                                            float v, int j) {
  if (v > kv[KN - 1] || (v == kv[KN - 1] && j < ki[KN - 1])) {
    float cv = v; int cj = j;
#pragma unroll
    for (int t = 0; t < KN; ++t) {
      bool b = (cv > kv[t]) || (cv == kv[t] && cj < ki[t]);
      float tv = kv[t]; int ti_ = ki[t];
      kv[t] = b ? cv : tv;  ki[t] = b ? cj : ti_;
      cv   = b ? tv : cv;   cj   = b ? ti_ : cj;
    }
  }
}

// ---------------------------------------------------------------------------
// k1f (fused): blocks [0, K1BLK) L2-normalize query rows -> qn (f32) + qh
// (bf16); blocks [K1BLK, K1BLK+16) compute the 64 class prototypes
// (4 classes/block, one wave per class), L2-normalized, stored TRANSPOSED
// protnT[d][c] so k3's per-lane-class reads are coalesced.
__global__ void k1f(const float* __restrict__ x, float* __restrict__ qn,
                    short* __restrict__ qh, float* __restrict__ protnT) {
  int lane = threadIdx.x & 63;
  int wv   = threadIdx.x >> 6;
  int blk  = blockIdx.x;

  if (blk < K1BLK) {                       // ---- qnorm path ----
    int r = blk * 4 + wv;
    int xr = (r >> 7) * XROW + KSHOT + (r & 127);
    const float* src = x + (size_t)xr * D;
    float v0 = src[lane], v1 = src[64 + lane];
    float ss = v0 * v0 + v1 * v1;
#pragma unroll
    for (int off = 1; off < 64; off <<= 1) ss += __shfl_xor(ss, off);
    float rn = 1.0f / fmaxf(sqrtf(ss), EPSV);
    float q0 = v0 * rn, q1 = v1 * rn;
    qn[(size_t)r * D + lane]      = q0;
    qn[(size_t)r * D + 64 + lane] = q1;
    __hip_bfloat16 h0 = __float2bfloat16(q0);
    __hip_bfloat16 h1 = __float2bfloat16(q1);
    qh[(size_t)r * D + lane]      = *(short*)&h0;
    qh[(size_t)r * D + 64 + lane] = *(short*)&h1;
  } else {                                 // ---- proto path ----
    int c = (blk - K1BLK) * 4 + wv;        // class 0..63
    const float* base = x + (size_t)(c * XROW) * D;
    float a0 = 0.f, a1 = 0.f;
#pragma unroll
    for (int s = 0; s < KSHOT; ++s) {
      a0 += base[s * D + lane];
      a1 += base[s * D + 64 + lane];
    }
    a0 *= 0.2f; a1 *= 0.2f;
    float ss = a0 * a0 + a1 * a1;
#pragma unroll
    for (int off = 1; off < 64; off <<= 1) ss += __shfl_xor(ss, off);
    float rn = 1.0f / fmaxf(sqrtf(ss), EPSV);
    protnT[lane * NCLS + c]        = a0 * rn;
    protnT[(lane + 64) * NCLS + c] = a1 * rn;
  }
}

// ---------------------------------------------------------------------------
// k2f: bf16 MFMA + threshold filter. 512 thr / 8 waves, 256 i-rows/block
// (each wave: 2 i-subs sharing each A-frag ds_read). LDS-staged double-
// buffered j-tile (waves 0-3 stage, all 8 compute), LDS per-row counters,
// per-(row, j-split) segments of packed (bf16(v)<<16|j).
// D layout (m89-verified): i-col = lane&15, j-row = (lane>>4)*4 + reg.
__global__ __launch_bounds__(512) void
k2f(const short* __restrict__ qh, int* __restrict__ segcnt,
    unsigned* __restrict__ cand) {
  __shared__ __align__(16) short jh[2][16 * D];   // 2 x 4 KB j-tile
  __shared__ int lcnt[BI];

  const int tid  = threadIdx.x;
  const int l    = tid & 63;
  const int w    = tid >> 6;               // wave 0..7
  const int ib   = blockIdx.x >> 4;        // 32 i-strips of 256
  const int js   = blockIdx.x & (SJ - 1);  // 16 j-splits
  const int i0   = ib * BI;
  const int j0s  = js * JPB;

  if (tid < BI) lcnt[tid] = 0;

  const bf16v8* qh8 = (const bf16v8*)qh;
  const int lg   = l >> 4;                 // k-group 0..3
  const int arow = l & 15;
  const int lrow = w * 16 + arow;          // local row 0..127 (i-sub 0)
  const int myi  = i0 + lrow;              // i-sub 0 row
  const int myi2 = myi + 128;              // i-sub 1 row

  bf16v8 bh[4], bg[4];
#pragma unroll
  for (int kk = 0; kk < 4; ++kk) {
    bh[kk] = qh8[(size_t)myi  * 16 + kk * 4 + lg];
    bg[kk] = qh8[(size_t)myi2 * 16 + kk * 4 + lg];
  }

  const bool stager = (tid < 256);         // waves 0-3 (wave-uniform)
  const int srow = (tid >> 4) & 15;
  const int schk = tid & 15;
  const int sslot = srow * 16 + (schk ^ (srow & 7));
  int rslot[4];
#pragma unroll
  for (int kk = 0; kk < 4; ++kk)
    rslot[kk] = arow * 16 + ((kk * 4 + lg) ^ (arow & 7));

  unsigned* seg  = cand + ((size_t)myi  * SJ + js) * CAPB;
  unsigned* seg2 = cand + ((size_t)myi2 * SJ + js) * CAPB;

  bf16v8 sa = {};
  if (stager) {
    sa = qh8[(size_t)(j0s + srow) * 16 + schk];
    ((bf16v8*)jh[0])[sslot] = sa;
    sa = qh8[(size_t)(j0s + 16 + srow) * 16 + schk];
  }
  __syncthreads();                         // covers lcnt init + buf0

  for (int t = 0; t < NTIL; ++t) {
    if (stager && t + 1 < NTIL) {
      ((bf16v8*)jh[(t + 1) & 1])[sslot] = sa;
      if (t + 2 < NTIL)
        sa = qh8[(size_t)(j0s + (t + 2) * 16 + srow) * 16 + schk];
    }

    const bf16v8* H = (const bf16v8*)jh[t & 1];
    f32v4 a0 = {0.f, 0.f, 0.f, 0.f};
    f32v4 a1 = {0.f, 0.f, 0.f, 0.f};
    f32v4 c0 = {0.f, 0.f, 0.f, 0.f};
    f32v4 c1 = {0.f, 0.f, 0.f, 0.f};
#pragma unroll
    for (int kk = 0; kk < 4; ++kk) {
      bf16v8 ah = H[rslot[kk]];            // one ds_read feeds both i-subs
      if (kk & 1) {
        a1 = __builtin_amdgcn_mfma_f32_16x16x32_bf16(ah, bh[kk], a1, 0, 0, 0);
        c1 = __builtin_amdgcn_mfma_f32_16x16x32_bf16(ah, bg[kk], c1, 0, 0, 0);
      } else {
        a0 = __builtin_amdgcn_mfma_f32_16x16x32_bf16(ah, bh[kk], a0, 0, 0, 0);
        c0 = __builtin_amdgcn_mfma_f32_16x16x32_bf16(ah, bg[kk], c0, 0, 0, 0);
      }
    }
    f32v4 s = a0 + a1;
    f32v4 r2 = c0 + c1;

    const int jb = j0s + t * 16 + lg * 4;
#pragma unroll
    for (int u = 0; u < 4; ++u) {
      if (s[u] >= TAU_LO) {                // ~0.9% of values
        int slot = atomicAdd(&lcnt[lrow], 1);
        if (slot < CAPB)
          seg[slot] = (__float_as_uint(s[u]) & 0xFFFF0000u) | (unsigned)(jb + u);
      }
      if (r2[u] >= TAU_LO) {
        int slot = atomicAdd(&lcnt[lrow + 128], 1);
        if (slot < CAPB)
          seg2[slot] = (__float_as_uint(r2[u]) & 0xFFFF0000u) | (unsigned)(jb + u);
      }
    }

    __syncthreads();   // readers of buf[t&1] done; writes to buf[(t+1)&1] visible
  }

  if (tid < BI)
    segcnt[(size_t)(i0 + tid) * SJ + js] = lcnt[tid];
}

// ---------------------------------------------------------------------------
// k_rr (R23/R25 body): serial re-dot, register-minimal (VGPR 32, occ 47%);
// dead-round skip + 9-step bisection.
__global__ void k_rr(const float* __restrict__ qn, const int* __restrict__ segcnt,
                     const unsigned* __restrict__ cand,
                     float* __restrict__ kval, int* __restrict__ kidx) {
  __shared__ float qi_s[4][D];
  int lane = threadIdx.x & 63;
  int wv   = threadIdx.x >> 6;
  int i = blockIdx.x * 4 + wv;

  float qi0 = qn[(size_t)i * D + lane];
  float qi1 = qn[(size_t)i * D + 64 + lane];

  // --- segment counts + prefix scan (lanes 0..15) ---
  int sc = (lane < SJ) ? segcnt[(size_t)i * SJ + lane] : 0;
  bool bad = __any(lane < SJ && sc > CAPB);
  int pre = sc;
#pragma unroll
  for (int off = 1; off < 16; off <<= 1) {
    int o = __shfl_up(pre, off, 16);
    if ((lane & 15) >= off) pre += o;
  }
  int b[SJ];                               // inclusive prefix, all lanes
#pragma unroll
  for (int k = 0; k < SJ; ++k) b[k] = __shfl(pre, k);
  const int ct = b[SJ - 1];
  bad = bad || (ct < KTOP);
  const int nra = (ct + 63) >> 6;          // active rounds, wave-uniform

  // --- lane-parallel packed-pair load (dead rounds skipped, NO inserts) ---
  const unsigned* crow = cand + (size_t)i * SJ * CAPB;
  float vv[NRND]; int jj[NRND];
#pragma unroll
  for (int r = 0; r < NRND; ++r) {
    vv[r] = 0.f; jj[r] = 0;
    if (r < nra) {                         // wave-uniform guard, static index
      int t = r * 64 + lane;
      bool valid = t < ct;
      int s = 0, off = 0;
#pragma unroll
      for (int k = 0; k < SJ; ++k) {       // b nondecreasing -> cmov scan
        bool ge = t >= b[k];
        s   = ge ? k + 1 : s;
        off = ge ? b[k] : off;
      }
      unsigned u = valid ? crow[s * CAPB + (t - off)] : 0u;
      vv[r] = __uint_as_float(u & 0xFFFF0000u);  // exact bf16 payload (>=0)
      jj[r] = (int)(u & 8191u);
    }
  }

  // --- bisect 9th-largest stored value; stored in [bf16(0.21)=0x3E57, ~0x3F81]
  //     so [0x3E00, 0x3FFF] covers it; ct>=9 keeps the invariant at lo ---
  int lo = 0x3E00, hi = 0x3FFF;
  while (lo < hi) {                        // 9 uniform iterations
    int mid = (lo + hi + 1) >> 1;
    unsigned um = (unsigned)mid << 16;
    int cnt = 0;
#pragma unroll
    for (int r = 0; r < NRND; ++r)
      if (r < nra)
        cnt += (int)__popcll(__ballot(__float_as_uint(vv[r]) >= um));
    if (cnt >= KTOP) lo = mid; else hi = mid - 1;
  }
  const float th = __uint_as_float((unsigned)lo << 16) - 2.0f * EPS_STORE;

  // --- serial exact re-dot of the borderline set (~10/row; R19 v3 form) ---
  float kv[KTOP]; int ki[KTOP];
#pragma unroll
  for (int t = 0; t < KTOP; ++t) { kv[t] = -INFINITY; ki[t] = 0x7fffffff; }
  if (!bad) {
#pragma unroll
    for (int r = 0; r < NRND; ++r) {
      if (r >= nra) continue;              // wave-uniform
      unsigned long long mask = __ballot(vv[r] >= th);   // invalids are 0 < th
      while (mask) {
        int bl = (int)__ffsll((long long)mask) - 1;
        mask &= mask - 1;
        int jc = __shfl(jj[r], bl);        // wave-uniform
        float p = qi0 * qn[(size_t)jc * D + lane] +
                  qi1 * qn[(size_t)jc * D + 64 + lane];
#pragma unroll
        for (int off = 1; off < 64; off <<= 1) p += __shfl_xor(p, off);
        topk_insert<KTOP>(kv, ki, p, jc);
      }
    }
  }

  // --- certificate; else inline exact full-row fallback ---
  if (bad || kv[KTOP - 1] <= TAU_LO + EPS_DOT) {
    qi_s[wv][lane]      = qi0;
    qi_s[wv][64 + lane] = qi1;
#pragma unroll
    for (int t = 0; t < KTOP; ++t) { kv[t] = -INFINITY; ki[t] = 0x7fffffff; }
    const float4* qi4 = (const float4*)qi_s[wv];
    for (int jb = 0; jb < M; jb += 64) {
      int j = jb + lane;
      const float4* qj = (const float4*)(qn + (size_t)j * D);
      float dot = 0.f;
#pragma unroll 8
      for (int ch = 0; ch < 32; ++ch) {
        float4 a = qi4[ch], bq = qj[ch];
        dot += a.x * bq.x + a.y * bq.y + a.z * bq.z + a.w * bq.w;
      }
      topk_insert<KTOP>(kv, ki, dot, j);
    }
#pragma unroll
    for (int off = 1; off < 64; off <<= 1) {
      float pv[KTOP]; int pj[KTOP];
#pragma unroll
      for (int t = 0; t < KTOP; ++t) {
        pv[t] = __shfl_xor(kv[t], off);
        pj[t] = __shfl_xor(ki[t], off);
      }
#pragma unroll
      for (int t = 0; t < KTOP; ++t) topk_insert<KTOP>(kv, ki, pv[t], pj[t]);
    }
  }

  if (lane == 0) {
#pragma unroll
    for (int t = 0; t < KTOP; ++t) {
      kval[(size_t)i * KTOP + t] = kv[t];
      kidx[(size_t)i * KTOP + t] = ki[t];
    }
  }
}

// ---------------------------------------------------------------------------
// k3: mutual mask + softmax over <=9 entries + adapted query + normalize +
// project on normalized prototypes, scale by tao. One wave per query row.
__global__ void k3_out(const float* __restrict__ x, const float* __restrict__ kval,
                       const int* __restrict__ kidx, const float* __restrict__ protnT,
                       const float* __restrict__ taop, float* __restrict__ out) {
  __shared__ float sw[4][KTOP];
  __shared__ int   sj[4][KTOP];
  __shared__ float an[4][D];
  int lane = threadIdx.x & 63;
  int wv   = threadIdx.x >> 6;
  int i = blockIdx.x * 4 + wv;

  float v = -INFINITY; int jt = 0; bool mut = false;
  if (lane < KTOP) {
    v  = kval[(size_t)i * KTOP + lane];
    jt = kidx[(size_t)i * KTOP + lane];
    const int* oj = kidx + (size_t)jt * KTOP;
#pragma unroll
    for (int t = 0; t < KTOP; ++t) mut = mut || (oj[t] == i);
  }
  float lv = mut ? v : -INFINITY;
#pragma unroll
  for (int off = 1; off < 16; off <<= 1) lv = fmaxf(lv, __shfl_xor(lv, off));
  float wexp = mut ? expf(v - lv) : 0.f;    // self is always mutual -> z >= 1
  float z = wexp;
#pragma unroll
  for (int off = 1; off < 16; off <<= 1) z += __shfl_xor(z, off);
  if (lane < KTOP) { sw[wv][lane] = wexp / z; sj[wv][lane] = jt; }
  __syncthreads();

  float a0 = 0.f, a1 = 0.f;
#pragma unroll
  for (int t = 0; t < KTOP; ++t) {
    float wt = sw[wv][t];
    if (wt != 0.f) {
      int j = sj[wv][t];
      int xr = (j >> 7) * XROW + KSHOT + (j & 127);
      const float* qr = x + (size_t)xr * D;
      a0 += wt * qr[lane];
      a1 += wt * qr[64 + lane];
    }
  }
  float ss = a0 * a0 + a1 * a1;
#pragma unroll
  for (int off = 1; off < 64; off <<= 1) ss += __shfl_xor(ss, off);
  float rn = 1.0f / fmaxf(sqrtf(ss), EPSV);
  an[wv][lane]      = a0 * rn;
  an[wv][64 + lane] = a1 * rn;
  __syncthreads();

  float acc = 0.f;
#pragma unroll 8
  for (int d = 0; d < D; ++d) acc += an[wv][d] * protnT[d * NCLS + lane];
  out[(size_t)i * NCLS + lane] = taop[0] * acc;
}

// ---------------------------------------------------------------------------
extern "C" void kernel_launch(void* const* d_in, const int* in_sizes, int n_in,
                              void* d_out, int out_size, void* d_ws, size_t ws_size,
                              hipStream_t stream) {
  const float* x   = (const float*)d_in[0];
  const float* tao = (const float*)d_in[1];
  float* out = (float*)d_out;

  // workspace layout, ~19.5 MB total
  float*    qn     = (float*)d_ws;                    // 8192*128 f32 (4 MB)
  short*    qh     = (short*)(qn + (size_t)M * D);    // 2 MB bf16
  int*      segcnt = (int*)(qh + (size_t)M * D);      // 8192*16 = 512 KB
  unsigned* cand   = (unsigned*)(segcnt + (size_t)M * SJ);  // 12.6 MB packed
  float*    kval   = (float*)(cand + (size_t)M * SJ * CAPB);
  int*      kidx   = (int*)(kval + (size_t)M * KTOP);
  float*    protnT = (float*)(kidx + (size_t)M * KTOP);     // 128*64

  k1f<<<K1BLK + NCLS / 4, 256, 0, stream>>>(x, qn, qh, protnT);
  k2f<<<(M / BI) * SJ, 512, 0, stream>>>(qh, segcnt, cand);
  k_rr<<<M / 4, 256, 0, stream>>>(qn, segcnt, cand, kval, kidx);
  k3_out<<<M / 4, 256, 0, stream>>>(x, kval, kidx, protnT, tao, out);
}